// Round 2
// baseline (845.587 us; speedup 1.0000x reference)
//
#include <hip/hip_runtime.h>
#include <hip/hip_bf16.h>
#include <cstdint>

// ---------------------------------------------------------------------------
// GAT 3-layer forward. N=50000 nodes, E=800000 edges, H=4 heads, D=64.
// Per layer: feat = h@W  ->  el/er  ->  per-dst softmax over incoming edges
//            -> weighted aggregate of feat[src] -> +bias -> (elu)
// CSR built per-launch (deterministic work; atomic bucket order only perturbs
// fp summation order, well below threshold).
// ---------------------------------------------------------------------------

#define FEAT 256   // H*D = 256 = F_IN for all three layers
#define NHEAD 4

// ---------------- CSR build ----------------
__global__ void hist_kernel(const int* __restrict__ dst, int* __restrict__ deg, int E) {
    int e = blockIdx.x * 256 + threadIdx.x;
    if (e < E) atomicAdd(&deg[dst[e]], 1);
}

__global__ void scan_block(const int* __restrict__ deg, int* __restrict__ offs,
                           int* __restrict__ bsums, int n) {
    __shared__ int s[256];
    int i = blockIdx.x * 256 + threadIdx.x;
    int v = (i < n) ? deg[i] : 0;
    s[threadIdx.x] = v; __syncthreads();
    #pragma unroll
    for (int off = 1; off < 256; off <<= 1) {
        int t = (threadIdx.x >= off) ? s[threadIdx.x - off] : 0;
        __syncthreads();
        s[threadIdx.x] += t;
        __syncthreads();
    }
    if (i < n) offs[i] = s[threadIdx.x] - v;          // block-local exclusive
    if (threadIdx.x == 255) bsums[blockIdx.x] = s[255];
}

__global__ void scan_sums(int* __restrict__ bsums, int nb) {  // one block
    __shared__ int s[256];
    int v = (threadIdx.x < nb) ? bsums[threadIdx.x] : 0;
    s[threadIdx.x] = v; __syncthreads();
    #pragma unroll
    for (int off = 1; off < 256; off <<= 1) {
        int t = (threadIdx.x >= off) ? s[threadIdx.x - off] : 0;
        __syncthreads();
        s[threadIdx.x] += t;
        __syncthreads();
    }
    if (threadIdx.x < nb) bsums[threadIdx.x] = s[threadIdx.x] - v;  // exclusive
}

__global__ void scan_add(int* __restrict__ offs, int* __restrict__ cursor,
                         const int* __restrict__ bsums, int n, int total) {
    int i = blockIdx.x * 256 + threadIdx.x;
    if (i < n) {
        int o = offs[i] + bsums[i >> 8];
        offs[i] = o;
        cursor[i] = o;
    }
    if (i == 0) offs[n] = total;
}

__global__ void scatter_kernel(const int* __restrict__ src, const int* __restrict__ dst,
                               int* __restrict__ cursor, int* __restrict__ csr_src, int E) {
    int e = blockIdx.x * 256 + threadIdx.x;
    if (e < E) {
        int d = dst[e];
        int pos = atomicAdd(&cursor[d], 1);
        csr_src[pos] = src[e];
    }
}

// ---------------- GEMM: C[M,256] = A[M,256] @ W[256,256] (f32) ----------------
#define BM 128
#define BN 64
#define BK 32

__global__ __launch_bounds__(256) void gemm_f32(const float* __restrict__ A,
                                                const float* __restrict__ W,
                                                float* __restrict__ C, int M) {
    __shared__ float As[BK][BM];   // transposed: As[k][m]
    __shared__ float Bs[BK][BN];
    const int tid = threadIdx.x;
    const int tx = tid & 15;       // col group: 4 cols each
    const int ty = tid >> 4;       // row group: 8 rows each
    const int row0 = blockIdx.x * BM;
    const int col0 = blockIdx.y * BN;

    const int a_r = tid >> 1;           // 0..127
    const int a_c = (tid & 1) * 16;     // 0 or 16
    const int b_r = tid >> 3;           // 0..31
    const int b_c = (tid & 7) * 8;      // 0..56

    float acc[8][4];
    #pragma unroll
    for (int i = 0; i < 8; ++i)
        #pragma unroll
        for (int j = 0; j < 4; ++j) acc[i][j] = 0.f;

    for (int k0 = 0; k0 < 256; k0 += BK) {
        float4 av[4];
        const int grow = row0 + a_r;
        if (grow < M) {
            const float4* Ap = (const float4*)(A + (size_t)grow * FEAT + k0 + a_c);
            av[0] = Ap[0]; av[1] = Ap[1]; av[2] = Ap[2]; av[3] = Ap[3];
        } else {
            av[0] = av[1] = av[2] = av[3] = make_float4(0.f, 0.f, 0.f, 0.f);
        }
        const float4* Wp = (const float4*)(W + (size_t)(k0 + b_r) * FEAT + col0 + b_c);
        float4 bv0 = Wp[0], bv1 = Wp[1];

        __syncthreads();
        #pragma unroll
        for (int j = 0; j < 4; ++j) {
            const float* a4 = (const float*)&av[j];
            As[a_c + j * 4 + 0][a_r] = a4[0];
            As[a_c + j * 4 + 1][a_r] = a4[1];
            As[a_c + j * 4 + 2][a_r] = a4[2];
            As[a_c + j * 4 + 3][a_r] = a4[3];
        }
        *((float4*)&Bs[b_r][b_c])     = bv0;
        *((float4*)&Bs[b_r][b_c + 4]) = bv1;
        __syncthreads();

        #pragma unroll
        for (int k = 0; k < BK; ++k) {
            float a[8], b[4];
            *(float4*)&a[0] = *(const float4*)&As[k][ty * 8];
            *(float4*)&a[4] = *(const float4*)&As[k][ty * 8 + 4];
            *(float4*)&b[0] = *(const float4*)&Bs[k][tx * 4];
            #pragma unroll
            for (int i = 0; i < 8; ++i)
                #pragma unroll
                for (int j = 0; j < 4; ++j)
                    acc[i][j] = fmaf(a[i], b[j], acc[i][j]);
        }
    }
    #pragma unroll
    for (int i = 0; i < 8; ++i) {
        int grow = row0 + ty * 8 + i;
        if (grow < M) {
            float4 o = make_float4(acc[i][0], acc[i][1], acc[i][2], acc[i][3]);
            *((float4*)(C + (size_t)grow * FEAT + col0 + tx * 4)) = o;
        }
    }
}

// ---------------- el/er: el[n,h] = sum_d feat[n,h,d]*al[h,d] ----------------
__global__ __launch_bounds__(256) void elr_kernel(const float* __restrict__ feat,
                                                  const float* __restrict__ al,
                                                  const float* __restrict__ ar,
                                                  float* __restrict__ el,
                                                  float* __restrict__ er, int n) {
    int node = blockIdx.x * 4 + (threadIdx.x >> 6);
    if (node >= n) return;
    int lane = threadIdx.x & 63;
    int f = lane * 4;                       // 4 contiguous feats, one head
    float4 v = *(const float4*)(feat + (size_t)node * FEAT + f);
    float4 a = *(const float4*)(al + f);
    float4 r = *(const float4*)(ar + f);
    float pl = v.x * a.x + v.y * a.y + v.z * a.z + v.w * a.w;
    float pr = v.x * r.x + v.y * r.y + v.z * r.z + v.w * r.w;
    #pragma unroll
    for (int off = 1; off < 16; off <<= 1) {   // reduce within 16-lane head group
        pl += __shfl_xor(pl, off, 64);
        pr += __shfl_xor(pr, off, 64);
    }
    if ((lane & 15) == 0) {
        int h = lane >> 4;
        el[node * NHEAD + h] = pl;
        er[node * NHEAD + h] = pr;
    }
}

// ---------------- per-dst softmax + aggregate (one wave per node) ----------------
__global__ __launch_bounds__(256) void agg_kernel(const float* __restrict__ feat,
                                                  const float* __restrict__ el,
                                                  const float* __restrict__ er,
                                                  const int* __restrict__ offs,
                                                  const int* __restrict__ csr_src,
                                                  const float* __restrict__ bias,
                                                  float* __restrict__ out,
                                                  int n, int act) {
    int node = blockIdx.x * 4 + (threadIdx.x >> 6);
    if (node >= n) return;
    int lane = threadIdx.x & 63;
    int h = lane >> 4;
    int f = lane * 4;
    int start = offs[node], end = offs[node + 1];
    float erh = er[node * NHEAD + h];

    // pass 1: max of leaky_relu(el[src]+er[dst]) over incoming edges
    float m = -1e30f;
    for (int p = start; p < end; ++p) {
        int s = csr_src[p];
        float e = el[s * NHEAD + h] + erh;
        e = (e > 0.f) ? e : 0.2f * e;
        m = fmaxf(m, e);
    }
    // pass 2: w = exp(e-m); s += w; acc += w*feat[src]; normalize at the end
    float ssum = 0.f;
    float acc0 = 0.f, acc1 = 0.f, acc2 = 0.f, acc3 = 0.f;
    for (int p = start; p < end; ++p) {
        int s = csr_src[p];
        float e = el[s * NHEAD + h] + erh;
        e = (e > 0.f) ? e : 0.2f * e;
        float w = __expf(e - m);
        ssum += w;
        float4 v = *(const float4*)(feat + (size_t)s * FEAT + f);
        acc0 = fmaf(w, v.x, acc0);
        acc1 = fmaf(w, v.y, acc1);
        acc2 = fmaf(w, v.z, acc2);
        acc3 = fmaf(w, v.w, acc3);
    }
    float inv = 1.f / fmaxf(ssum, 1e-9f);
    float4 b4 = *(const float4*)(bias + f);
    float o0 = fmaf(acc0, inv, b4.x);
    float o1 = fmaf(acc1, inv, b4.y);
    float o2 = fmaf(acc2, inv, b4.z);
    float o3 = fmaf(acc3, inv, b4.w);
    if (act) {
        o0 = (o0 > 0.f) ? o0 : expm1f(o0);
        o1 = (o1 > 0.f) ? o1 : expm1f(o1);
        o2 = (o2 > 0.f) ? o2 : expm1f(o2);
        o3 = (o3 > 0.f) ? o3 : expm1f(o3);
    }
    *((float4*)(out + (size_t)node * FEAT + f)) = make_float4(o0, o1, o2, o3);
}

// ---------------------------------------------------------------------------
extern "C" void kernel_launch(void* const* d_in, const int* in_sizes, int n_in,
                              void* d_out, int out_size, void* d_ws, size_t ws_size,
                              hipStream_t stream) {
    const float* features = (const float*)d_in[0];
    const int*   src      = (const int*)d_in[1];
    const int*   dst      = (const int*)d_in[2];
    const int N = in_sizes[0] / FEAT;
    const int E = in_sizes[1];

    // ---- carve workspace ----
    char* ws = (char*)d_ws;
    size_t off = 0;
    auto carve = [&](size_t bytes) -> void* {
        void* p = ws + off;
        off = (off + bytes + 255) & ~(size_t)255;
        return p;
    };
    int*   deg     = (int*)carve((size_t)N * 4);
    int*   offs    = (int*)carve((size_t)(N + 1) * 4);
    int*   cursor  = (int*)carve((size_t)N * 4);
    int*   bsums   = (int*)carve(4096);
    int*   csr_src = (int*)carve((size_t)E * 4);
    float* el      = (float*)carve((size_t)N * NHEAD * 4);
    float* er      = (float*)carve((size_t)N * NHEAD * 4);
    float* featX   = (float*)carve((size_t)N * FEAT * 4);
    float* hY      = (float*)carve((size_t)N * FEAT * 4);

    const int nbE = (E + 255) / 256;
    const int nbN = (N + 255) / 256;

    // ---- CSR build (once; graph static across layers) ----
    hipMemsetAsync(deg, 0, (size_t)N * 4, stream);
    hist_kernel<<<nbE, 256, 0, stream>>>(dst, deg, E);
    scan_block<<<nbN, 256, 0, stream>>>(deg, offs, bsums, N);
    scan_sums<<<1, 256, 0, stream>>>(bsums, nbN);
    scan_add<<<nbN, 256, 0, stream>>>(offs, cursor, bsums, N, E);
    scatter_kernel<<<nbE, 256, 0, stream>>>(src, dst, cursor, csr_src, E);

    dim3 ggrid((N + BM - 1) / BM, FEAT / BN);
    const int nodeBlocks = (N + 3) / 4;

    // ---- layer 1 ----
    gemm_f32<<<ggrid, 256, 0, stream>>>(features, (const float*)d_in[3], featX, N);
    elr_kernel<<<nodeBlocks, 256, 0, stream>>>(featX, (const float*)d_in[4],
                                               (const float*)d_in[5], el, er, N);
    agg_kernel<<<nodeBlocks, 256, 0, stream>>>(featX, el, er, offs, csr_src,
                                               (const float*)d_in[6], hY, N, 1);
    // ---- layer 2 ----
    gemm_f32<<<ggrid, 256, 0, stream>>>(hY, (const float*)d_in[7], featX, N);
    elr_kernel<<<nodeBlocks, 256, 0, stream>>>(featX, (const float*)d_in[8],
                                               (const float*)d_in[9], el, er, N);
    agg_kernel<<<nodeBlocks, 256, 0, stream>>>(featX, el, er, offs, csr_src,
                                               (const float*)d_in[10], hY, N, 1);
    // ---- layer 3 ----
    gemm_f32<<<ggrid, 256, 0, stream>>>(hY, (const float*)d_in[11], featX, N);
    elr_kernel<<<nodeBlocks, 256, 0, stream>>>(featX, (const float*)d_in[12],
                                               (const float*)d_in[13], el, er, N);
    agg_kernel<<<nodeBlocks, 256, 0, stream>>>(featX, el, er, offs, csr_src,
                                               (const float*)d_in[14], (float*)d_out, N, 0);
}

// Round 6
// 632.538 us; speedup vs baseline: 1.3368x; 1.3368x over previous
//
#include <hip/hip_runtime.h>
#include <hip/hip_bf16.h>
#include <cstdint>

// ---------------------------------------------------------------------------
// GAT 3-layer forward. N=50000, E=800000, H=4, D=64 (FEAT = H*D = 256 = F_IN).
// R2: GEMM -> bf16x3 MFMA (split-precision, f32-accurate), agg -> edge-parallel
//     softmax phases + unrolled independent gathers (attack latency).
// ---------------------------------------------------------------------------

#define FEAT 256
#define NHEAD 4

typedef short short8 __attribute__((ext_vector_type(8)));
typedef float f32x4 __attribute__((ext_vector_type(4)));

__device__ __forceinline__ ushort f2bf(float v) {
    uint u = __float_as_uint(v);
    uint r = (u + 0x7fffu + ((u >> 16) & 1u)) >> 16;
    return (ushort)r;
}
__device__ __forceinline__ float bf2f(ushort h) {
    return __uint_as_float(((uint)h) << 16);
}

// ---------------- CSR build ----------------
__global__ void hist_kernel(const int* __restrict__ dst, int* __restrict__ deg, int E) {
    int e = blockIdx.x * 256 + threadIdx.x;
    if (e < E) atomicAdd(&deg[dst[e]], 1);
}

__global__ void scan_block(const int* __restrict__ deg, int* __restrict__ offs,
                           int* __restrict__ bsums, int n) {
    __shared__ int s[256];
    int i = blockIdx.x * 256 + threadIdx.x;
    int v = (i < n) ? deg[i] : 0;
    s[threadIdx.x] = v; __syncthreads();
    #pragma unroll
    for (int off = 1; off < 256; off <<= 1) {
        int t = (threadIdx.x >= off) ? s[threadIdx.x - off] : 0;
        __syncthreads();
        s[threadIdx.x] += t;
        __syncthreads();
    }
    if (i < n) offs[i] = s[threadIdx.x] - v;
    if (threadIdx.x == 255) bsums[blockIdx.x] = s[255];
}

__global__ void scan_sums(int* __restrict__ bsums, int nb) {
    __shared__ int s[256];
    int v = (threadIdx.x < nb) ? bsums[threadIdx.x] : 0;
    s[threadIdx.x] = v; __syncthreads();
    #pragma unroll
    for (int off = 1; off < 256; off <<= 1) {
        int t = (threadIdx.x >= off) ? s[threadIdx.x - off] : 0;
        __syncthreads();
        s[threadIdx.x] += t;
        __syncthreads();
    }
    if (threadIdx.x < nb) bsums[threadIdx.x] = s[threadIdx.x] - v;
}

__global__ void scan_add(int* __restrict__ offs, int* __restrict__ cursor,
                         const int* __restrict__ bsums, int n, int total) {
    int i = blockIdx.x * 256 + threadIdx.x;
    if (i < n) {
        int o = offs[i] + bsums[i >> 8];
        offs[i] = o;
        cursor[i] = o;
    }
    if (i == 0) offs[n] = total;
}

__global__ void scatter_kernel(const int* __restrict__ src, const int* __restrict__ dst,
                               int* __restrict__ cursor, int* __restrict__ csr_src, int E) {
    int e = blockIdx.x * 256 + threadIdx.x;
    if (e < E) {
        int d = dst[e];
        int pos = atomicAdd(&cursor[d], 1);
        csr_src[pos] = src[e];
    }
}

// ---------------- W prep: split f32 W[k][n] -> bf16 hi/lo, transposed [n][k] ----
__global__ void wprep_kernel(const float* __restrict__ W,
                             ushort* __restrict__ Wh, ushort* __restrict__ Wl) {
    int n = blockIdx.x;     // 256 blocks
    int k = threadIdx.x;    // 256 threads
    float v = W[(size_t)k * FEAT + n];
    ushort h = f2bf(v);
    float r = v - bf2f(h);
    Wh[(size_t)n * FEAT + k] = h;
    Wl[(size_t)n * FEAT + k] = f2bf(r);
}

// ---------------- GEMM: C[M,256] = A[M,256] @ W, bf16x3 MFMA ----------------
#define GBM 128
#define GBN 128
#define GBK 32
#define LDK 40   // padded K stride (bf16 elems): 80 B rows

__global__ __launch_bounds__(256) void gemm_bf16x3(const float* __restrict__ A,
                                                   const ushort* __restrict__ Wh,
                                                   const ushort* __restrict__ Wl,
                                                   float* __restrict__ C, int M) {
    __shared__ ushort Ah[GBM][LDK];
    __shared__ ushort Al[GBM][LDK];
    __shared__ ushort Bh[GBN][LDK];
    __shared__ ushort Bl[GBN][LDK];

    const int tid  = threadIdx.x;
    const int lane = tid & 63;
    const int wid  = tid >> 6;
    const int wm   = (wid >> 1) * 64;     // wave row offset in tile
    const int wn   = (wid & 1) * 64;      // wave col offset in tile
    const int row0 = blockIdx.x * GBM;
    const int col0 = blockIdx.y * GBN;

    const int ar = tid >> 1;              // A stage row 0..127
    const int aq = (tid & 1) * 16;        // A stage k offset 0/16
    const int bn = tid & 127;             // W stage col(n) 0..127
    const int bq = (tid >> 7) * 16;       // W stage k offset 0/16

    const int fr = lane & 15;             // fragment row/col within 16
    const int fk = (lane >> 4) * 8;       // fragment k offset

    f32x4 acc[4][4];
    #pragma unroll
    for (int i = 0; i < 4; ++i)
        #pragma unroll
        for (int j = 0; j < 4; ++j) {
            f32x4 z = {0.f, 0.f, 0.f, 0.f};
            acc[i][j] = z;
        }

    for (int k0 = 0; k0 < FEAT; k0 += GBK) {
        // ---- issue global loads ----
        float4 av[4];
        if (row0 + ar < M) {
            const float4* Ap = (const float4*)(A + (size_t)(row0 + ar) * FEAT + k0 + aq);
            av[0] = Ap[0]; av[1] = Ap[1]; av[2] = Ap[2]; av[3] = Ap[3];
        } else {
            av[0] = av[1] = av[2] = av[3] = make_float4(0.f, 0.f, 0.f, 0.f);
        }
        const short8* Whp = (const short8*)(Wh + (size_t)(col0 + bn) * FEAT + k0 + bq);
        const short8* Wlp = (const short8*)(Wl + (size_t)(col0 + bn) * FEAT + k0 + bq);
        short8 wh0 = Whp[0], wh1 = Whp[1];
        short8 wl0 = Wlp[0], wl1 = Wlp[1];

        __syncthreads();   // previous iteration's LDS reads done

        // ---- split A to hi/lo bf16 and stage ----
        ushort hi[16], lo[16];
        #pragma unroll
        for (int j = 0; j < 4; ++j) {
            const float* v4 = (const float*)&av[j];
            #pragma unroll
            for (int t = 0; t < 4; ++t) {
                float v = v4[t];
                ushort h = f2bf(v);
                hi[j * 4 + t] = h;
                lo[j * 4 + t] = f2bf(v - bf2f(h));
            }
        }
        *(short8*)&Ah[ar][aq]     = *(short8*)&hi[0];
        *(short8*)&Ah[ar][aq + 8] = *(short8*)&hi[8];
        *(short8*)&Al[ar][aq]     = *(short8*)&lo[0];
        *(short8*)&Al[ar][aq + 8] = *(short8*)&lo[8];
        *(short8*)&Bh[bn][bq]     = wh0;
        *(short8*)&Bh[bn][bq + 8] = wh1;
        *(short8*)&Bl[bn][bq]     = wl0;
        *(short8*)&Bl[bn][bq + 8] = wl1;

        __syncthreads();

        // ---- fragments + MFMA ----
        short8 afh[4], afl[4], bfh[4], bfl[4];
        #pragma unroll
        for (int t = 0; t < 4; ++t) {
            afh[t] = *(const short8*)&Ah[wm + t * 16 + fr][fk];
            afl[t] = *(const short8*)&Al[wm + t * 16 + fr][fk];
            bfh[t] = *(const short8*)&Bh[wn + t * 16 + fr][fk];
            bfl[t] = *(const short8*)&Bl[wn + t * 16 + fr][fk];
        }
        #pragma unroll
        for (int mt = 0; mt < 4; ++mt)
            #pragma unroll
            for (int nt = 0; nt < 4; ++nt) {
                acc[mt][nt] = __builtin_amdgcn_mfma_f32_16x16x32_bf16(
                    afh[mt], bfh[nt], acc[mt][nt], 0, 0, 0);
                acc[mt][nt] = __builtin_amdgcn_mfma_f32_16x16x32_bf16(
                    afh[mt], bfl[nt], acc[mt][nt], 0, 0, 0);
                acc[mt][nt] = __builtin_amdgcn_mfma_f32_16x16x32_bf16(
                    afl[mt], bfh[nt], acc[mt][nt], 0, 0, 0);
            }
    }

    // ---- epilogue: C[row][col], row=(lane>>4)*4+reg, col=lane&15 ----
    #pragma unroll
    for (int mt = 0; mt < 4; ++mt) {
        #pragma unroll
        for (int r = 0; r < 4; ++r) {
            int row = row0 + wm + mt * 16 + (lane >> 4) * 4 + r;
            if (row < M) {
                #pragma unroll
                for (int nt = 0; nt < 4; ++nt) {
                    C[(size_t)row * FEAT + col0 + wn + nt * 16 + fr] = acc[mt][nt][r];
                }
            }
        }
    }
}

// ---------------- el/er ----------------
__global__ __launch_bounds__(256) void elr_kernel(const float* __restrict__ feat,
                                                  const float* __restrict__ al,
                                                  const float* __restrict__ ar,
                                                  float* __restrict__ el,
                                                  float* __restrict__ er, int n) {
    int node = blockIdx.x * 4 + (threadIdx.x >> 6);
    if (node >= n) return;
    int lane = threadIdx.x & 63;
    int f = lane * 4;
    float4 v = *(const float4*)(feat + (size_t)node * FEAT + f);
    float4 a = *(const float4*)(al + f);
    float4 r = *(const float4*)(ar + f);
    float pl = v.x * a.x + v.y * a.y + v.z * a.z + v.w * a.w;
    float pr = v.x * r.x + v.y * r.y + v.z * r.z + v.w * r.w;
    #pragma unroll
    for (int off = 1; off < 16; off <<= 1) {
        pl += __shfl_xor(pl, off, 64);
        pr += __shfl_xor(pr, off, 64);
    }
    if ((lane & 15) == 0) {
        int h = lane >> 4;
        el[node * NHEAD + h] = pl;
        er[node * NHEAD + h] = pr;
    }
}

// ---------------- per-dst softmax + aggregate (edge-parallel phases) ----------------
__global__ __launch_bounds__(256) void agg_kernel(const float* __restrict__ feat,
                                                  const float* __restrict__ el,
                                                  const float* __restrict__ er,
                                                  const int* __restrict__ offs,
                                                  const int* __restrict__ csr_src,
                                                  const float* __restrict__ bias,
                                                  float* __restrict__ out,
                                                  int n, int act) {
    int node = blockIdx.x * 4 + (threadIdx.x >> 6);
    if (node >= n) return;
    int lane = threadIdx.x & 63;
    int h = lane >> 4;
    int j16 = lane & 15;
    int f = lane * 4;
    int start = offs[node];
    int deg = offs[node + 1] - start;
    float erh = er[node * NHEAD + h];

    // pass 1: edge-parallel max (16 edges at a time per head group)
    float m = -1e30f;
    for (int p0 = 0; p0 < deg; p0 += 16) {
        int p = p0 + j16;
        float e = -1e30f;
        if (p < deg) {
            int s = csr_src[start + p];
            e = el[s * NHEAD + h] + erh;
            e = (e > 0.f) ? e : 0.2f * e;
        }
        m = fmaxf(m, e);
    }
    #pragma unroll
    for (int off = 1; off < 16; off <<= 1) m = fmaxf(m, __shfl_xor(m, off, 64));

    // pass 2: edge-parallel w, then broadcast + independent gathers
    float ssum = 0.f;
    float acc0 = 0.f, acc1 = 0.f, acc2 = 0.f, acc3 = 0.f;
    for (int p0 = 0; p0 < deg; p0 += 16) {
        int p = p0 + j16;
        float w = 0.f;
        int sidx = 0;
        if (p < deg) {
            sidx = csr_src[start + p];
            float e = el[sidx * NHEAD + h] + erh;
            e = (e > 0.f) ? e : 0.2f * e;
            w = __expf(e - m);
        }
        ssum += w;
        int cnt = min(16, deg - p0);
        if (cnt == 16) {
            #pragma unroll
            for (int j = 0; j < 16; ++j) {
                float wj = __shfl(w, j, 16);
                int sj = __shfl(sidx, j, 16);
                float4 v = *(const float4*)(feat + (size_t)sj * FEAT + f);
                acc0 = fmaf(wj, v.x, acc0);
                acc1 = fmaf(wj, v.y, acc1);
                acc2 = fmaf(wj, v.z, acc2);
                acc3 = fmaf(wj, v.w, acc3);
            }
        } else {
            for (int j = 0; j < cnt; ++j) {
                float wj = __shfl(w, j, 16);
                int sj = __shfl(sidx, j, 16);
                float4 v = *(const float4*)(feat + (size_t)sj * FEAT + f);
                acc0 = fmaf(wj, v.x, acc0);
                acc1 = fmaf(wj, v.y, acc1);
                acc2 = fmaf(wj, v.z, acc2);
                acc3 = fmaf(wj, v.w, acc3);
            }
        }
    }
    #pragma unroll
    for (int off = 1; off < 16; off <<= 1) ssum += __shfl_xor(ssum, off, 64);

    float inv = 1.f / fmaxf(ssum, 1e-9f);
    float4 b4 = *(const float4*)(bias + f);
    float o0 = fmaf(acc0, inv, b4.x);
    float o1 = fmaf(acc1, inv, b4.y);
    float o2 = fmaf(acc2, inv, b4.z);
    float o3 = fmaf(acc3, inv, b4.w);
    if (act) {
        o0 = (o0 > 0.f) ? o0 : expm1f(o0);
        o1 = (o1 > 0.f) ? o1 : expm1f(o1);
        o2 = (o2 > 0.f) ? o2 : expm1f(o2);
        o3 = (o3 > 0.f) ? o3 : expm1f(o3);
    }
    *((float4*)(out + (size_t)node * FEAT + f)) = make_float4(o0, o1, o2, o3);
}

// ---------------------------------------------------------------------------
extern "C" void kernel_launch(void* const* d_in, const int* in_sizes, int n_in,
                              void* d_out, int out_size, void* d_ws, size_t ws_size,
                              hipStream_t stream) {
    const float* features = (const float*)d_in[0];
    const int*   src      = (const int*)d_in[1];
    const int*   dst      = (const int*)d_in[2];
    const int N = in_sizes[0] / FEAT;
    const int E = in_sizes[1];

    // ---- carve workspace ----
    char* ws = (char*)d_ws;
    size_t off = 0;
    auto carve = [&](size_t bytes) -> void* {
        void* p = ws + off;
        off = (off + bytes + 255) & ~(size_t)255;
        return p;
    };
    int*    deg     = (int*)carve((size_t)N * 4);
    int*    offs    = (int*)carve((size_t)(N + 1) * 4);
    int*    cursor  = (int*)carve((size_t)N * 4);
    int*    bsums   = (int*)carve(4096);
    int*    csr_src = (int*)carve((size_t)E * 4);
    float*  el      = (float*)carve((size_t)N * NHEAD * 4);
    float*  er      = (float*)carve((size_t)N * NHEAD * 4);
    float*  featX   = (float*)carve((size_t)N * FEAT * 4);
    float*  hY      = (float*)carve((size_t)N * FEAT * 4);
    ushort* Wh[3], *Wl[3];
    for (int i = 0; i < 3; ++i) {
        Wh[i] = (ushort*)carve((size_t)FEAT * FEAT * 2);
        Wl[i] = (ushort*)carve((size_t)FEAT * FEAT * 2);
    }

    const int nbE = (E + 255) / 256;
    const int nbN = (N + 255) / 256;

    // ---- CSR build + W prep ----
    hipMemsetAsync(deg, 0, (size_t)N * 4, stream);
    hist_kernel<<<nbE, 256, 0, stream>>>(dst, deg, E);
    scan_block<<<nbN, 256, 0, stream>>>(deg, offs, bsums, N);
    scan_sums<<<1, 256, 0, stream>>>(bsums, nbN);
    scan_add<<<nbN, 256, 0, stream>>>(offs, cursor, bsums, N, E);
    scatter_kernel<<<nbE, 256, 0, stream>>>(src, dst, cursor, csr_src, E);
    wprep_kernel<<<FEAT, FEAT, 0, stream>>>((const float*)d_in[3],  Wh[0], Wl[0]);
    wprep_kernel<<<FEAT, FEAT, 0, stream>>>((const float*)d_in[7],  Wh[1], Wl[1]);
    wprep_kernel<<<FEAT, FEAT, 0, stream>>>((const float*)d_in[11], Wh[2], Wl[2]);

    dim3 ggrid((N + GBM - 1) / GBM, FEAT / GBN);
    const int nodeBlocks = (N + 3) / 4;

    // ---- layer 1 ----
    gemm_bf16x3<<<ggrid, 256, 0, stream>>>(features, Wh[0], Wl[0], featX, N);
    elr_kernel<<<nodeBlocks, 256, 0, stream>>>(featX, (const float*)d_in[4],
                                               (const float*)d_in[5], el, er, N);
    agg_kernel<<<nodeBlocks, 256, 0, stream>>>(featX, el, er, offs, csr_src,
                                               (const float*)d_in[6], hY, N, 1);
    // ---- layer 2 ----
    gemm_bf16x3<<<ggrid, 256, 0, stream>>>(hY, Wh[1], Wl[1], featX, N);
    elr_kernel<<<nodeBlocks, 256, 0, stream>>>(featX, (const float*)d_in[8],
                                               (const float*)d_in[9], el, er, N);
    agg_kernel<<<nodeBlocks, 256, 0, stream>>>(featX, el, er, offs, csr_src,
                                               (const float*)d_in[10], hY, N, 1);
    // ---- layer 3 ----
    gemm_bf16x3<<<ggrid, 256, 0, stream>>>(hY, Wh[2], Wl[2], featX, N);
    elr_kernel<<<nodeBlocks, 256, 0, stream>>>(featX, (const float*)d_in[12],
                                               (const float*)d_in[13], el, er, N);
    agg_kernel<<<nodeBlocks, 256, 0, stream>>>(featX, el, er, offs, csr_src,
                                               (const float*)d_in[14], (float*)d_out, N, 0);
}

// Round 7
// 543.098 us; speedup vs baseline: 1.5570x; 1.1647x over previous
//
#include <hip/hip_runtime.h>
#include <hip/hip_bf16.h>
#include <cstdint>

// ---------------------------------------------------------------------------
// GAT 3-layer forward. N=50000, E=800000, H=4, D=64 (FEAT = H*D = 256 = F_IN).
// R7: agg -> online-softmax single pass + index prefetch; layers 1-2 gather
//     feat as bf16 (featB written by elr), layer 3 gathers f32.
// ---------------------------------------------------------------------------

#define FEAT 256
#define NHEAD 4

typedef short short8 __attribute__((ext_vector_type(8)));
typedef float f32x4 __attribute__((ext_vector_type(4)));

__device__ __forceinline__ ushort f2bf(float v) {
    uint u = __float_as_uint(v);
    uint r = (u + 0x7fffu + ((u >> 16) & 1u)) >> 16;
    return (ushort)r;
}
__device__ __forceinline__ float bf2f(ushort h) {
    return __uint_as_float(((uint)h) << 16);
}

// ---------------- CSR build ----------------
__global__ void hist_kernel(const int* __restrict__ dst, int* __restrict__ deg, int E) {
    int e = blockIdx.x * 256 + threadIdx.x;
    if (e < E) atomicAdd(&deg[dst[e]], 1);
}

__global__ void scan_block(const int* __restrict__ deg, int* __restrict__ offs,
                           int* __restrict__ bsums, int n) {
    __shared__ int s[256];
    int i = blockIdx.x * 256 + threadIdx.x;
    int v = (i < n) ? deg[i] : 0;
    s[threadIdx.x] = v; __syncthreads();
    #pragma unroll
    for (int off = 1; off < 256; off <<= 1) {
        int t = (threadIdx.x >= off) ? s[threadIdx.x - off] : 0;
        __syncthreads();
        s[threadIdx.x] += t;
        __syncthreads();
    }
    if (i < n) offs[i] = s[threadIdx.x] - v;
    if (threadIdx.x == 255) bsums[blockIdx.x] = s[255];
}

__global__ void scan_sums(int* __restrict__ bsums, int nb) {
    __shared__ int s[256];
    int v = (threadIdx.x < nb) ? bsums[threadIdx.x] : 0;
    s[threadIdx.x] = v; __syncthreads();
    #pragma unroll
    for (int off = 1; off < 256; off <<= 1) {
        int t = (threadIdx.x >= off) ? s[threadIdx.x - off] : 0;
        __syncthreads();
        s[threadIdx.x] += t;
        __syncthreads();
    }
    if (threadIdx.x < nb) bsums[threadIdx.x] = s[threadIdx.x] - v;
}

__global__ void scan_add(int* __restrict__ offs, int* __restrict__ cursor,
                         const int* __restrict__ bsums, int n, int total) {
    int i = blockIdx.x * 256 + threadIdx.x;
    if (i < n) {
        int o = offs[i] + bsums[i >> 8];
        offs[i] = o;
        cursor[i] = o;
    }
    if (i == 0) offs[n] = total;
}

__global__ void scatter_kernel(const int* __restrict__ src, const int* __restrict__ dst,
                               int* __restrict__ cursor, int* __restrict__ csr_src, int E) {
    int e = blockIdx.x * 256 + threadIdx.x;
    if (e < E) {
        int d = dst[e];
        int pos = atomicAdd(&cursor[d], 1);
        csr_src[pos] = src[e];
    }
}

// ---------------- W prep: split f32 W[k][n] -> bf16 hi/lo, transposed [n][k] ----
__global__ void wprep_kernel(const float* __restrict__ W,
                             ushort* __restrict__ Wh, ushort* __restrict__ Wl) {
    int n = blockIdx.x;     // 256 blocks
    int k = threadIdx.x;    // 256 threads
    float v = W[(size_t)k * FEAT + n];
    ushort h = f2bf(v);
    float r = v - bf2f(h);
    Wh[(size_t)n * FEAT + k] = h;
    Wl[(size_t)n * FEAT + k] = f2bf(r);
}

// ---------------- GEMM: C[M,256] = A[M,256] @ W, bf16x3 MFMA ----------------
#define GBM 128
#define GBN 128
#define GBK 32
#define LDK 40   // padded K stride (bf16 elems): 80 B rows

__global__ __launch_bounds__(256) void gemm_bf16x3(const float* __restrict__ A,
                                                   const ushort* __restrict__ Wh,
                                                   const ushort* __restrict__ Wl,
                                                   float* __restrict__ C, int M) {
    __shared__ ushort Ah[GBM][LDK];
    __shared__ ushort Al[GBM][LDK];
    __shared__ ushort Bh[GBN][LDK];
    __shared__ ushort Bl[GBN][LDK];

    const int tid  = threadIdx.x;
    const int lane = tid & 63;
    const int wid  = tid >> 6;
    const int wm   = (wid >> 1) * 64;     // wave row offset in tile
    const int wn   = (wid & 1) * 64;      // wave col offset in tile
    const int row0 = blockIdx.x * GBM;
    const int col0 = blockIdx.y * GBN;

    const int ar = tid >> 1;              // A stage row 0..127
    const int aq = (tid & 1) * 16;        // A stage k offset 0/16
    const int bn = tid & 127;             // W stage col(n) 0..127
    const int bq = (tid >> 7) * 16;       // W stage k offset 0/16

    const int fr = lane & 15;             // fragment row/col within 16
    const int fk = (lane >> 4) * 8;       // fragment k offset

    f32x4 acc[4][4];
    #pragma unroll
    for (int i = 0; i < 4; ++i)
        #pragma unroll
        for (int j = 0; j < 4; ++j) {
            f32x4 z = {0.f, 0.f, 0.f, 0.f};
            acc[i][j] = z;
        }

    for (int k0 = 0; k0 < FEAT; k0 += GBK) {
        // ---- issue global loads ----
        float4 av[4];
        if (row0 + ar < M) {
            const float4* Ap = (const float4*)(A + (size_t)(row0 + ar) * FEAT + k0 + aq);
            av[0] = Ap[0]; av[1] = Ap[1]; av[2] = Ap[2]; av[3] = Ap[3];
        } else {
            av[0] = av[1] = av[2] = av[3] = make_float4(0.f, 0.f, 0.f, 0.f);
        }
        const short8* Whp = (const short8*)(Wh + (size_t)(col0 + bn) * FEAT + k0 + bq);
        const short8* Wlp = (const short8*)(Wl + (size_t)(col0 + bn) * FEAT + k0 + bq);
        short8 wh0 = Whp[0], wh1 = Whp[1];
        short8 wl0 = Wlp[0], wl1 = Wlp[1];

        __syncthreads();   // previous iteration's LDS reads done

        // ---- split A to hi/lo bf16 and stage ----
        ushort hi[16], lo[16];
        #pragma unroll
        for (int j = 0; j < 4; ++j) {
            const float* v4 = (const float*)&av[j];
            #pragma unroll
            for (int t = 0; t < 4; ++t) {
                float v = v4[t];
                ushort h = f2bf(v);
                hi[j * 4 + t] = h;
                lo[j * 4 + t] = f2bf(v - bf2f(h));
            }
        }
        *(short8*)&Ah[ar][aq]     = *(short8*)&hi[0];
        *(short8*)&Ah[ar][aq + 8] = *(short8*)&hi[8];
        *(short8*)&Al[ar][aq]     = *(short8*)&lo[0];
        *(short8*)&Al[ar][aq + 8] = *(short8*)&lo[8];
        *(short8*)&Bh[bn][bq]     = wh0;
        *(short8*)&Bh[bn][bq + 8] = wh1;
        *(short8*)&Bl[bn][bq]     = wl0;
        *(short8*)&Bl[bn][bq + 8] = wl1;

        __syncthreads();

        // ---- fragments + MFMA ----
        short8 afh[4], afl[4], bfh[4], bfl[4];
        #pragma unroll
        for (int t = 0; t < 4; ++t) {
            afh[t] = *(const short8*)&Ah[wm + t * 16 + fr][fk];
            afl[t] = *(const short8*)&Al[wm + t * 16 + fr][fk];
            bfh[t] = *(const short8*)&Bh[wn + t * 16 + fr][fk];
            bfl[t] = *(const short8*)&Bl[wn + t * 16 + fr][fk];
        }
        #pragma unroll
        for (int mt = 0; mt < 4; ++mt)
            #pragma unroll
            for (int nt = 0; nt < 4; ++nt) {
                acc[mt][nt] = __builtin_amdgcn_mfma_f32_16x16x32_bf16(
                    afh[mt], bfh[nt], acc[mt][nt], 0, 0, 0);
                acc[mt][nt] = __builtin_amdgcn_mfma_f32_16x16x32_bf16(
                    afh[mt], bfl[nt], acc[mt][nt], 0, 0, 0);
                acc[mt][nt] = __builtin_amdgcn_mfma_f32_16x16x32_bf16(
                    afl[mt], bfh[nt], acc[mt][nt], 0, 0, 0);
            }
    }

    // ---- epilogue: C[row][col], row=(lane>>4)*4+reg, col=lane&15 ----
    #pragma unroll
    for (int mt = 0; mt < 4; ++mt) {
        #pragma unroll
        for (int r = 0; r < 4; ++r) {
            int row = row0 + wm + mt * 16 + (lane >> 4) * 4 + r;
            if (row < M) {
                #pragma unroll
                for (int nt = 0; nt < 4; ++nt) {
                    C[(size_t)row * FEAT + col0 + wn + nt * 16 + fr] = acc[mt][nt][r];
                }
            }
        }
    }
}

// ---------------- el/er (+ optional bf16 copy of feat for the gather) ----------------
__global__ __launch_bounds__(256) void elr_kernel(const float* __restrict__ feat,
                                                  const float* __restrict__ al,
                                                  const float* __restrict__ ar,
                                                  float* __restrict__ el,
                                                  float* __restrict__ er,
                                                  ushort* __restrict__ featB, int n) {
    int node = blockIdx.x * 4 + (threadIdx.x >> 6);
    if (node >= n) return;
    int lane = threadIdx.x & 63;
    int f = lane * 4;
    float4 v = *(const float4*)(feat + (size_t)node * FEAT + f);
    if (featB) {
        ushort4 b;
        b.x = f2bf(v.x); b.y = f2bf(v.y); b.z = f2bf(v.z); b.w = f2bf(v.w);
        *(ushort4*)(featB + (size_t)node * FEAT + f) = b;
    }
    float4 a = *(const float4*)(al + f);
    float4 r = *(const float4*)(ar + f);
    float pl = v.x * a.x + v.y * a.y + v.z * a.z + v.w * a.w;
    float pr = v.x * r.x + v.y * r.y + v.z * r.z + v.w * r.w;
    #pragma unroll
    for (int off = 1; off < 16; off <<= 1) {
        pl += __shfl_xor(pl, off, 64);
        pr += __shfl_xor(pr, off, 64);
    }
    if ((lane & 15) == 0) {
        int h = lane >> 4;
        el[node * NHEAD + h] = pl;
        er[node * NHEAD + h] = pr;
    }
}

// ---------------- online-softmax aggregate, bf16 gather (layers 1-2, ELU) ----------
__global__ __launch_bounds__(256) void agg_online_bf16(const ushort* __restrict__ featB,
                                                       const float* __restrict__ el,
                                                       const float* __restrict__ er,
                                                       const int* __restrict__ offs,
                                                       const int* __restrict__ csr_src,
                                                       const float* __restrict__ bias,
                                                       float* __restrict__ out, int n) {
    int node = blockIdx.x * 4 + (threadIdx.x >> 6);
    if (node >= n) return;
    int lane = threadIdx.x & 63;
    int h = lane >> 4;
    int j16 = lane & 15;
    int f = lane * 4;
    int start = offs[node];
    int deg = offs[node + 1] - start;
    float erh = er[node * NHEAD + h];

    float m = -1e30f, ssum = 0.f;
    float acc0 = 0.f, acc1 = 0.f, acc2 = 0.f, acc3 = 0.f;
    int sidx = (j16 < deg) ? csr_src[start + j16] : 0;

    for (int p0 = 0; p0 < deg; p0 += 16) {
        int pn = p0 + 16 + j16;
        int sidx_nx = (pn < deg) ? csr_src[start + pn] : 0;   // prefetch next chunk
        float e = -1e30f;
        if (p0 + j16 < deg) {
            float t = el[sidx * NHEAD + h] + erh;
            e = (t > 0.f) ? t : 0.2f * t;
        }
        float cm = e;
        #pragma unroll
        for (int o = 1; o < 16; o <<= 1) cm = fmaxf(cm, __shfl_xor(cm, o, 64));
        float newm = fmaxf(m, cm);
        float sc = __expf(m - newm);
        m = newm;
        ssum *= sc; acc0 *= sc; acc1 *= sc; acc2 *= sc; acc3 *= sc;
        float w = __expf(e - m);   // masked lanes: exp(-inf) = 0
        ssum += w;
        int cnt = min(16, deg - p0);
        if (cnt == 16) {
            #pragma unroll
            for (int j = 0; j < 16; ++j) {
                float wj = __shfl(w, j, 16);
                int sj = __shfl(sidx, j, 16);
                ushort4 v = *(const ushort4*)(featB + (size_t)sj * FEAT + f);
                acc0 = fmaf(wj, bf2f(v.x), acc0);
                acc1 = fmaf(wj, bf2f(v.y), acc1);
                acc2 = fmaf(wj, bf2f(v.z), acc2);
                acc3 = fmaf(wj, bf2f(v.w), acc3);
            }
        } else {
            for (int j = 0; j < cnt; ++j) {
                float wj = __shfl(w, j, 16);
                int sj = __shfl(sidx, j, 16);
                ushort4 v = *(const ushort4*)(featB + (size_t)sj * FEAT + f);
                acc0 = fmaf(wj, bf2f(v.x), acc0);
                acc1 = fmaf(wj, bf2f(v.y), acc1);
                acc2 = fmaf(wj, bf2f(v.z), acc2);
                acc3 = fmaf(wj, bf2f(v.w), acc3);
            }
        }
        sidx = sidx_nx;
    }
    float st = ssum;
    #pragma unroll
    for (int o = 1; o < 16; o <<= 1) st += __shfl_xor(st, o, 64);
    float inv = 1.f / fmaxf(st, 1e-9f);
    float4 b4 = *(const float4*)(bias + f);
    float o0 = fmaf(acc0, inv, b4.x);
    float o1 = fmaf(acc1, inv, b4.y);
    float o2 = fmaf(acc2, inv, b4.z);
    float o3 = fmaf(acc3, inv, b4.w);
    o0 = (o0 > 0.f) ? o0 : expm1f(o0);
    o1 = (o1 > 0.f) ? o1 : expm1f(o1);
    o2 = (o2 > 0.f) ? o2 : expm1f(o2);
    o3 = (o3 > 0.f) ? o3 : expm1f(o3);
    *((float4*)(out + (size_t)node * FEAT + f)) = make_float4(o0, o1, o2, o3);
}

// ---------------- online-softmax aggregate, f32 gather (layer 3, no act) ----------
__global__ __launch_bounds__(256) void agg_online_f32(const float* __restrict__ feat,
                                                      const float* __restrict__ el,
                                                      const float* __restrict__ er,
                                                      const int* __restrict__ offs,
                                                      const int* __restrict__ csr_src,
                                                      const float* __restrict__ bias,
                                                      float* __restrict__ out, int n) {
    int node = blockIdx.x * 4 + (threadIdx.x >> 6);
    if (node >= n) return;
    int lane = threadIdx.x & 63;
    int h = lane >> 4;
    int j16 = lane & 15;
    int f = lane * 4;
    int start = offs[node];
    int deg = offs[node + 1] - start;
    float erh = er[node * NHEAD + h];

    float m = -1e30f, ssum = 0.f;
    float acc0 = 0.f, acc1 = 0.f, acc2 = 0.f, acc3 = 0.f;
    int sidx = (j16 < deg) ? csr_src[start + j16] : 0;

    for (int p0 = 0; p0 < deg; p0 += 16) {
        int pn = p0 + 16 + j16;
        int sidx_nx = (pn < deg) ? csr_src[start + pn] : 0;
        float e = -1e30f;
        if (p0 + j16 < deg) {
            float t = el[sidx * NHEAD + h] + erh;
            e = (t > 0.f) ? t : 0.2f * t;
        }
        float cm = e;
        #pragma unroll
        for (int o = 1; o < 16; o <<= 1) cm = fmaxf(cm, __shfl_xor(cm, o, 64));
        float newm = fmaxf(m, cm);
        float sc = __expf(m - newm);
        m = newm;
        ssum *= sc; acc0 *= sc; acc1 *= sc; acc2 *= sc; acc3 *= sc;
        float w = __expf(e - m);
        ssum += w;
        int cnt = min(16, deg - p0);
        if (cnt == 16) {
            #pragma unroll
            for (int j = 0; j < 16; ++j) {
                float wj = __shfl(w, j, 16);
                int sj = __shfl(sidx, j, 16);
                float4 v = *(const float4*)(feat + (size_t)sj * FEAT + f);
                acc0 = fmaf(wj, v.x, acc0);
                acc1 = fmaf(wj, v.y, acc1);
                acc2 = fmaf(wj, v.z, acc2);
                acc3 = fmaf(wj, v.w, acc3);
            }
        } else {
            for (int j = 0; j < cnt; ++j) {
                float wj = __shfl(w, j, 16);
                int sj = __shfl(sidx, j, 16);
                float4 v = *(const float4*)(feat + (size_t)sj * FEAT + f);
                acc0 = fmaf(wj, v.x, acc0);
                acc1 = fmaf(wj, v.y, acc1);
                acc2 = fmaf(wj, v.z, acc2);
                acc3 = fmaf(wj, v.w, acc3);
            }
        }
        sidx = sidx_nx;
    }
    float st = ssum;
    #pragma unroll
    for (int o = 1; o < 16; o <<= 1) st += __shfl_xor(st, o, 64);
    float inv = 1.f / fmaxf(st, 1e-9f);
    float4 b4 = *(const float4*)(bias + f);
    float o0 = fmaf(acc0, inv, b4.x);
    float o1 = fmaf(acc1, inv, b4.y);
    float o2 = fmaf(acc2, inv, b4.z);
    float o3 = fmaf(acc3, inv, b4.w);
    *((float4*)(out + (size_t)node * FEAT + f)) = make_float4(o0, o1, o2, o3);
}

// ---------------------------------------------------------------------------
extern "C" void kernel_launch(void* const* d_in, const int* in_sizes, int n_in,
                              void* d_out, int out_size, void* d_ws, size_t ws_size,
                              hipStream_t stream) {
    const float* features = (const float*)d_in[0];
    const int*   src      = (const int*)d_in[1];
    const int*   dst      = (const int*)d_in[2];
    const int N = in_sizes[0] / FEAT;
    const int E = in_sizes[1];

    // ---- carve workspace ----
    char* ws = (char*)d_ws;
    size_t off = 0;
    auto carve = [&](size_t bytes) -> void* {
        void* p = ws + off;
        off = (off + bytes + 255) & ~(size_t)255;
        return p;
    };
    int*    deg     = (int*)carve((size_t)N * 4);
    int*    offs    = (int*)carve((size_t)(N + 1) * 4);
    int*    cursor  = (int*)carve((size_t)N * 4);
    int*    bsums   = (int*)carve(4096);
    int*    csr_src = (int*)carve((size_t)E * 4);
    float*  el      = (float*)carve((size_t)N * NHEAD * 4);
    float*  er      = (float*)carve((size_t)N * NHEAD * 4);
    float*  featX   = (float*)carve((size_t)N * FEAT * 4);
    float*  hY      = (float*)carve((size_t)N * FEAT * 4);
    ushort* featB   = (ushort*)carve((size_t)N * FEAT * 2);
    ushort* Wh[3], *Wl[3];
    for (int i = 0; i < 3; ++i) {
        Wh[i] = (ushort*)carve((size_t)FEAT * FEAT * 2);
        Wl[i] = (ushort*)carve((size_t)FEAT * FEAT * 2);
    }

    const int nbE = (E + 255) / 256;
    const int nbN = (N + 255) / 256;

    // ---- CSR build + W prep ----
    hipMemsetAsync(deg, 0, (size_t)N * 4, stream);
    hist_kernel<<<nbE, 256, 0, stream>>>(dst, deg, E);
    scan_block<<<nbN, 256, 0, stream>>>(deg, offs, bsums, N);
    scan_sums<<<1, 256, 0, stream>>>(bsums, nbN);
    scan_add<<<nbN, 256, 0, stream>>>(offs, cursor, bsums, N, E);
    scatter_kernel<<<nbE, 256, 0, stream>>>(src, dst, cursor, csr_src, E);
    wprep_kernel<<<FEAT, FEAT, 0, stream>>>((const float*)d_in[3],  Wh[0], Wl[0]);
    wprep_kernel<<<FEAT, FEAT, 0, stream>>>((const float*)d_in[7],  Wh[1], Wl[1]);
    wprep_kernel<<<FEAT, FEAT, 0, stream>>>((const float*)d_in[11], Wh[2], Wl[2]);

    dim3 ggrid((N + GBM - 1) / GBM, FEAT / GBN);
    const int nodeBlocks = (N + 3) / 4;

    // ---- layer 1 ----
    gemm_bf16x3<<<ggrid, 256, 0, stream>>>(features, Wh[0], Wl[0], featX, N);
    elr_kernel<<<nodeBlocks, 256, 0, stream>>>(featX, (const float*)d_in[4],
                                               (const float*)d_in[5], el, er, featB, N);
    agg_online_bf16<<<nodeBlocks, 256, 0, stream>>>(featB, el, er, offs, csr_src,
                                                    (const float*)d_in[6], hY, N);
    // ---- layer 2 ----
    gemm_bf16x3<<<ggrid, 256, 0, stream>>>(hY, Wh[1], Wl[1], featX, N);
    elr_kernel<<<nodeBlocks, 256, 0, stream>>>(featX, (const float*)d_in[8],
                                               (const float*)d_in[9], el, er, featB, N);
    agg_online_bf16<<<nodeBlocks, 256, 0, stream>>>(featB, el, er, offs, csr_src,
                                                    (const float*)d_in[10], hY, N);
    // ---- layer 3 ----
    gemm_bf16x3<<<ggrid, 256, 0, stream>>>(hY, Wh[2], Wl[2], featX, N);
    elr_kernel<<<nodeBlocks, 256, 0, stream>>>(featX, (const float*)d_in[12],
                                               (const float*)d_in[13], el, er, (ushort*)nullptr, N);
    agg_online_f32<<<nodeBlocks, 256, 0, stream>>>(featX, el, er, offs, csr_src,
                                                   (const float*)d_in[14], (float*)d_out, N);
}